// Round 14
// baseline (69.892 us; speedup 1.0000x reference)
//
#include <hip/hip_runtime.h>

#define PHI     1.618033988749895f
#define INV_PHI 0.6180339887498949f
#define NTILES  4

typedef _Float16 f16x8 __attribute__((ext_vector_type(8)));
typedef float    f32x4 __attribute__((ext_vector_type(4)));

typedef const __attribute__((address_space(1))) void gas_void;
typedef __attribute__((address_space(3))) void las_void;

__device__ __forceinline__ float phi_spiral(float v) {
    // sigmoid(v/phi) * (v*phi/(1+|v|)) = v*phi / ((1+e^{-v/phi})(1+|v|))
    float e = __expf(-v * INV_PHI);
    float d = (1.0f + e) * (1.0f + fabsf(v));
    return __fdividef(v * PHI, d);
}

// async global->LDS, 16B/lane (weights staging only)
__device__ __forceinline__ void cp16(const void* g, void* l) {
    __builtin_amdgcn_global_load_lds((gas_void*)g, (las_void*)l, 16, 0, 0);
}

// ---------------- workspace layout (fp16 elems; bytes = 2x) ----------------
#define WS_B1 0          // bytes [0,32K)    32 frags
#define WS_B2 16384      // bytes [32K,40K)   8 frags
#define WS_B3 20480      // bytes [40K,44K)   4 frags
#define WS_BIAS_BYTES 65536

// B-fragment lane layout for v_mfma_f32_16x16x32_f16 (verified, m89-m103):
// lane holds B[k][n], n = lane&15, k = (lane>>4)*8 + j.
__global__ void prep_kernel(
    const float* __restrict__ W_in, const float* __restrict__ b_in,
    const float* __restrict__ Wn,   const float* __restrict__ bn,
    const float* __restrict__ W_int,const float* __restrict__ b_int,
    _Float16* __restrict__ wsh, float* __restrict__ wsb)
{
    if (blockIdx.x == 11) {                      // padded biases
        const int t = threadIdx.x;
        if (t < 64)       wsb[t] = (t < 49)        ? b_in[t]        : 0.f;
        else if (t < 128) wsb[t] = (t - 64 < 49)   ? bn[t - 64]     : 0.f;
        else if (t < 160) wsb[t] = (t - 128 < 21)  ? b_int[t - 128] : 0.f;
        return;
    }
    const int g    = blockIdx.x * 256 + threadIdx.x;   // 0..2815
    const int lane = g & 63;
    const int fid  = g >> 6;                            // 0..43
    const int lr = lane & 15, lk = lane >> 4;
    f16x8 o;
    if (fid < 32) {                       // stage 1: W_in[49,256]
        const int ks = fid >> 2, nt = fid & 3;
        const int n = nt * 16 + lr, kb = ks * 32 + lk * 8;
#pragma unroll 8
        for (int j = 0; j < 8; ++j) {
            const int k = kb + j;
            o[j] = (_Float16)((n < 49) ? W_in[n * 256 + k] : 0.f);
        }
        *reinterpret_cast<f16x8*>(wsh + WS_B1 + (size_t)(fid * 64 + lane) * 8) = o;
    } else if (fid < 40) {                // stage 2: Wn flat [49,49]
        const int f = fid - 32, ks = f >> 2, nt = f & 3;
        const int n = nt * 16 + lr, kb = ks * 32 + lk * 8;
#pragma unroll 8
        for (int j = 0; j < 8; ++j) {
            const int k = kb + j;
            o[j] = (_Float16)((n < 49 && k < 49) ? Wn[n * 49 + k] : 0.f);
        }
        *reinterpret_cast<f16x8*>(wsh + WS_B2 + (size_t)(f * 64 + lane) * 8) = o;
    } else {                              // stage 3: W_int[21,49]
        const int f = fid - 40, ks = f >> 1, nt = f & 1;
        const int n = nt * 16 + lr, kb = ks * 32 + lk * 8;
#pragma unroll 8
        for (int j = 0; j < 8; ++j) {
            const int k = kb + j;
            o[j] = (_Float16)((n < 21 && k < 49) ? W_int[n * 49 + k] : 0.f);
        }
        *reinterpret_cast<f16x8*>(wsh + WS_B3 + (size_t)(f * 64 + lane) * 8) = o;
    }
}

// Issue one half-tile (K=128) of x into DST[8] f32x4 regs (static indices).
// Half g: tile g>>1, col base (g&1)*128. Lane (lr,lk): row lr, cols lk*8+...
#define ISSUE_HALF(DST, G) do {                                                   \
    const float* _s = xw + (size_t)((G) >> 1) * 65536 + ((G) & 1) * 128 + lk * 8; \
    _Pragma("unroll 4")                                                           \
    for (int kk = 0; kk < 4; ++kk) {                                              \
        DST[2 * kk]     = *reinterpret_cast<const f32x4*>(_s + kk * 32);          \
        DST[2 * kk + 1] = *reinterpret_cast<const f32x4*>(_s + kk * 32 + 4);      \
    } } while (0)

// Consume one half-tile: 4 k-steps x 4 MFMA, B1 frags (ks KS0+kk) from LDS.
#define COMPUTE_HALF(SRC, KS0) do {                                               \
    _Pragma("unroll 4")                                                           \
    for (int kk = 0; kk < 4; ++kk) {                                              \
        const f16x8 a = { (_Float16)SRC[2*kk][0],   (_Float16)SRC[2*kk][1],       \
                          (_Float16)SRC[2*kk][2],   (_Float16)SRC[2*kk][3],       \
                          (_Float16)SRC[2*kk+1][0], (_Float16)SRC[2*kk+1][1],     \
                          (_Float16)SRC[2*kk+1][2], (_Float16)SRC[2*kk+1][3] };   \
        _Pragma("unroll 4")                                                       \
        for (int nt = 0; nt < 4; ++nt) {                                          \
            const f16x8 bf = *reinterpret_cast<const f16x8*>(                     \
                ldsW + (size_t)(((KS0) + kk) * 4 + nt) * 1024 + lane * 16);       \
            acc1[nt] = __builtin_amdgcn_mfma_f32_16x16x32_f16(a, bf, acc1[nt],    \
                                                              0, 0, 0);           \
        } } } while (0)

// 1024 thr = 16 waves, 1 block/CU (grid 256), 16 rows/wave x NTILES=4 tiles.
// x path is REGISTER-staged (T14): two 32-VGPR half-tile buffers xA/xB;
// next half's 8 dwordx4 issued at the top of the current half -> tile i+1's
// first half is in flight THROUGH tile i's serial tail (R13's idle-BW gap).
// Compiler manages vmcnt (register deps). No x LDS, no asm waits, no swizzle.
// LDS 84 KB: [0,44K) B1|B2|B3 weights (staged once), 16 x 2560B work slots
// (H fp16 [16][72] / integ fp32 [16][25] overlay). One barrier total.
__global__ __launch_bounds__(1024)
__attribute__((amdgpu_waves_per_eu(4, 4)))
void seven_neurons_mfma(
    const float* __restrict__ x,
    const _Float16* __restrict__ wsh, const float* __restrict__ wsb,
    const float* __restrict__ gamma, const float* __restrict__ beta,
    const float* __restrict__ W_out, const float* __restrict__ b_out,
    float* __restrict__ out)
{
    __shared__ __align__(16) unsigned char lds[45056 + 16 * 2560];  // 84 KB

    const int t = threadIdx.x;
    const int lane = t & 63, wv = t >> 6;                // wv 0..15
    const int lr = lane & 15, lk = lane >> 4;

    unsigned char* ldsW  = lds;                          // B1@0, B2@32K, B3@40K
    unsigned char* wslot = lds + 45056 + wv * 2560;      // H/integ work area

    // ---- biases
    float b1v[4], b2v[4], b3v[2];
#pragma unroll 4
    for (int nt = 0; nt < 4; ++nt) { b1v[nt] = wsb[nt * 16 + lr]; b2v[nt] = wsb[64 + nt * 16 + lr]; }
#pragma unroll 2
    for (int nt = 0; nt < 2; ++nt) b3v[nt] = wsb[128 + nt * 16 + lr];

    // ---- stage ALL weight fragments (44 x 1KB) once, then publish
    const unsigned char* wsrc = (const unsigned char*)wsh;
#pragma unroll 1
    for (int f = wv; f < 44; f += 16)
        cp16(wsrc + (size_t)f * 1024 + lane * 16, ldsW + (size_t)f * 1024);
    __syncthreads();                                     // drains vmcnt: weights visible

    // per-lane x row base: this wave's rows are (block*NTILES*256 + wv*16 + lr)
    const float* xw = x + ((size_t)blockIdx.x * NTILES * 256 + wv * 16 + lr) * 256;

    f32x4 xA[8], xB[8];
    ISSUE_HALF(xA, 0);                                   // tile 0, half 0

#pragma unroll 1
    for (int it = 0; it < NTILES; ++it) {
        f32x4 acc1[4];
#pragma unroll 4
        for (int ni = 0; ni < 4; ++ni) acc1[ni] = (f32x4){0.f, 0.f, 0.f, 0.f};

        // half 0: compute xA, prefetch half 1 into xB
        ISSUE_HALF(xB, 2 * it + 1);
        COMPUTE_HALF(xA, 0);
        // half 1: compute xB, prefetch NEXT TILE half 0 into xA (pre-tail!)
        if (it + 1 < NTILES) ISSUE_HALF(xA, 2 * it + 2);
        COMPUTE_HALF(xB, 4);

        // ---- epilogue 1: H fp16 [16][72] (wave-private)
        {
            _Float16* H = (_Float16*)wslot;
#pragma unroll 4
            for (int nt = 0; nt < 4; ++nt)
#pragma unroll 4
                for (int r = 0; r < 4; ++r) {
                    const int row = lk * 4 + r;                  // 0..15
                    const float v = phi_spiral(acc1[nt][r] + b1v[nt]);
                    H[row * 72 + nt * 16 + lr] = (_Float16)v;
                }
        }

        // ---- stage 2: comb = spiral(h @ Wn^T + b2), K=64
        f32x4 acc2[4];
#pragma unroll 4
        for (int ni = 0; ni < 4; ++ni) acc2[ni] = (f32x4){0.f, 0.f, 0.f, 0.f};
#pragma unroll 2
        for (int ks = 0; ks < 2; ++ks) {
            const f16x8 a = *reinterpret_cast<const f16x8*>(
                wslot + lr * 144 + (ks * 32 + lk * 8) * 2);
#pragma unroll 4
            for (int nt = 0; nt < 4; ++nt) {
                const f16x8 bf = *reinterpret_cast<const f16x8*>(
                    ldsW + 32768 + (size_t)((ks * 4 + nt) * 64 + lane) * 16);
                acc2[nt] = __builtin_amdgcn_mfma_f32_16x16x32_f16(a, bf, acc2[nt], 0, 0, 0);
            }
        }
        {
            _Float16* H = (_Float16*)wslot;
#pragma unroll 4
            for (int nt = 0; nt < 4; ++nt)
#pragma unroll 4
                for (int r = 0; r < 4; ++r) {
                    const int row = lk * 4 + r;
                    const float v = phi_spiral(acc2[nt][r] + b2v[nt]);
                    H[row * 72 + nt * 16 + lr] = (_Float16)v;
                }
        }

        // ---- stage 3: integ = spiral(comb @ W_int^T + b3), K=64, N=32
        f32x4 acc3[2];
#pragma unroll 2
        for (int ni = 0; ni < 2; ++ni) acc3[ni] = (f32x4){0.f, 0.f, 0.f, 0.f};
#pragma unroll 2
        for (int ks = 0; ks < 2; ++ks) {
            const f16x8 a = *reinterpret_cast<const f16x8*>(
                wslot + lr * 144 + (ks * 32 + lk * 8) * 2);
#pragma unroll 2
            for (int nt = 0; nt < 2; ++nt) {
                const f16x8 bf = *reinterpret_cast<const f16x8*>(
                    ldsW + 40960 + (size_t)((ks * 2 + nt) * 64 + lane) * 16);
                acc3[nt] = __builtin_amdgcn_mfma_f32_16x16x32_f16(a, bf, acc3[nt], 0, 0, 0);
            }
        }
        // ---- epilogue 3: integ fp32 [16][25] overlays H (in-wave ordering)
        {
            float* F = (float*)wslot;
#pragma unroll 2
            for (int nt = 0; nt < 2; ++nt)
#pragma unroll 4
                for (int r = 0; r < 4; ++r) {
                    const int col = nt * 16 + lr;
                    const int row = lk * 4 + r;
                    if (col < 21)
                        F[row * 25 + col] = phi_spiral(acc3[nt][r] + b3v[nt]);
                }
        }

        // ---- LayerNorm(21) + out: 4 threads/row, wave-private (r>>4 == wv)
        {
            const int r = t >> 2, p = t & 3;
            const float* my = (const float*)(lds + 45056 + (size_t)(r >> 4) * 2560)
                              + (r & 15) * 25;
            float v[21];
#pragma unroll 21
            for (int o = 0; o < 21; ++o) v[o] = my[o];
            float mu = 0.f;
#pragma unroll 21
            for (int o = 0; o < 21; ++o) mu += v[o];
            mu *= (1.0f / 21.0f);
            float var = 0.f;
#pragma unroll 21
            for (int o = 0; o < 21; ++o) { float d = v[o] - mu; var = fmaf(d, d, var); }
            var *= (1.0f / 21.0f);
            const float rs = rsqrtf(var + 1e-5f);
            float acc = b_out[p];
#pragma unroll 21
            for (int o = 0; o < 21; ++o)
                acc = fmaf((v[o] - mu) * rs * gamma[o] + beta[o], W_out[p * 21 + o], acc);
            out[((size_t)blockIdx.x * NTILES + it) * 1024 + t] = acc;
        }
    }
}

extern "C" void kernel_launch(void* const* d_in, const int* in_sizes, int n_in,
                              void* d_out, int out_size, void* d_ws, size_t ws_size,
                              hipStream_t stream) {
    const float* x     = (const float*)d_in[0];
    const float* W_in  = (const float*)d_in[1];
    const float* b_in  = (const float*)d_in[2];
    const float* Wn    = (const float*)d_in[3];
    const float* bn    = (const float*)d_in[4];
    const float* W_int = (const float*)d_in[5];
    const float* b_int = (const float*)d_in[6];
    const float* gamma = (const float*)d_in[7];
    const float* beta  = (const float*)d_in[8];
    const float* W_out = (const float*)d_in[9];
    const float* b_out = (const float*)d_in[10];
    float* out = (float*)d_out;

    _Float16* wsh = (_Float16*)d_ws;
    float*    wsb = (float*)((char*)d_ws + WS_BIAS_BYTES);

    prep_kernel<<<12, 256, 0, stream>>>(W_in, b_in, Wn, bn, W_int, b_int, wsh, wsb);

    const int B = in_sizes[0] / 256;          // 262144 = 256 blocks x 4 tiles x 256 rows
    seven_neurons_mfma<<<B / (NTILES * 256), 1024, 0, stream>>>(
        x, wsh, wsb, gamma, beta, W_out, b_out, out);
}

// Round 15
// 59.271 us; speedup vs baseline: 1.1792x; 1.1792x over previous
//
#include <hip/hip_runtime.h>

#define PHI     1.618033988749895f
#define INV_PHI 0.6180339887498949f
#define NTILES  4

typedef _Float16 f16x8 __attribute__((ext_vector_type(8)));
typedef float    f32x4 __attribute__((ext_vector_type(4)));

typedef const __attribute__((address_space(1))) void gas_void;
typedef __attribute__((address_space(3))) void las_void;

__device__ __forceinline__ float phi_spiral(float v) {
    // sigmoid(v/phi) * (v*phi/(1+|v|)) = v*phi / ((1+e^{-v/phi})(1+|v|))
    float e = __expf(-v * INV_PHI);
    float d = (1.0f + e) * (1.0f + fabsf(v));
    return __fdividef(v * PHI, d);
}

// async global->LDS, 16B/lane. LDS dest = wave-uniform base + lane*16;
// global src is per-lane (m104).
__device__ __forceinline__ void cp16(const void* g, void* l) {
    __builtin_amdgcn_global_load_lds((gas_void*)g, (las_void*)l, 16, 0, 0);
}

// ---------------- workspace layout (fp16 elems; bytes = 2x) ----------------
#define WS_B1 0          // bytes [0,32K)    32 frags
#define WS_B2 16384      // bytes [32K,40K)   8 frags
#define WS_B3 20480      // bytes [40K,44K)   4 frags
#define WS_BIAS_BYTES 65536

// B-fragment lane layout for v_mfma_f32_16x16x32_f16 (verified, m89-m103):
// lane holds B[k][n], n = lane&15, k = (lane>>4)*8 + j.
__global__ void prep_kernel(
    const float* __restrict__ W_in, const float* __restrict__ b_in,
    const float* __restrict__ Wn,   const float* __restrict__ bn,
    const float* __restrict__ W_int,const float* __restrict__ b_int,
    _Float16* __restrict__ wsh, float* __restrict__ wsb)
{
    if (blockIdx.x == 11) {                      // padded biases
        const int t = threadIdx.x;
        if (t < 64)       wsb[t] = (t < 49)        ? b_in[t]        : 0.f;
        else if (t < 128) wsb[t] = (t - 64 < 49)   ? bn[t - 64]     : 0.f;
        else if (t < 160) wsb[t] = (t - 128 < 21)  ? b_int[t - 128] : 0.f;
        return;
    }
    const int g    = blockIdx.x * 256 + threadIdx.x;   // 0..2815
    const int lane = g & 63;
    const int fid  = g >> 6;                            // 0..43
    const int lr = lane & 15, lk = lane >> 4;
    f16x8 o;
    if (fid < 32) {                       // stage 1: W_in[49,256]
        const int ks = fid >> 2, nt = fid & 3;
        const int n = nt * 16 + lr, kb = ks * 32 + lk * 8;
#pragma unroll 8
        for (int j = 0; j < 8; ++j) {
            const int k = kb + j;
            o[j] = (_Float16)((n < 49) ? W_in[n * 256 + k] : 0.f);
        }
        *reinterpret_cast<f16x8*>(wsh + WS_B1 + (size_t)(fid * 64 + lane) * 8) = o;
    } else if (fid < 40) {                // stage 2: Wn flat [49,49]
        const int f = fid - 32, ks = f >> 2, nt = f & 3;
        const int n = nt * 16 + lr, kb = ks * 32 + lk * 8;
#pragma unroll 8
        for (int j = 0; j < 8; ++j) {
            const int k = kb + j;
            o[j] = (_Float16)((n < 49 && k < 49) ? Wn[n * 49 + k] : 0.f);
        }
        *reinterpret_cast<f16x8*>(wsh + WS_B2 + (size_t)(f * 64 + lane) * 8) = o;
    } else {                              // stage 3: W_int[21,49]
        const int f = fid - 40, ks = f >> 1, nt = f & 1;
        const int n = nt * 16 + lr, kb = ks * 32 + lk * 8;
#pragma unroll 8
        for (int j = 0; j < 8; ++j) {
            const int k = kb + j;
            o[j] = (_Float16)((n < 21 && k < 49) ? W_int[n * 49 + k] : 0.f);
        }
        *reinterpret_cast<f16x8*>(wsh + WS_B3 + (size_t)(f * 64 + lane) * 8) = o;
    }
}

// 1024 thr = 16 waves, 1 block/CU (grid 256). Each wave: 16 rows/tile x
// NTILES=4 tiles, chunk pipeline CONTINUOUS across tiles (x dbuf disjoint
// from H/integ work area -> stream never stops during the stage-2/3/LN tail).
// LDS 148 KB: [0,44K) B1|B2|B3 (staged once; main loop's only VMEM = x-DMAs
// + out-stores), then 16 x 6656B wave slots: [0,4K) x dbuf, [4K,6.5K) work.
// One barrier total (publish weights). All later LDS traffic wave-private.
// vmcnt invariant: the 2 newest VMEM entries always include chunk g+1's DMAs
// (stores interleave as NEWER entries -> vmcnt(2) stays conservative-safe).
__global__ __launch_bounds__(1024)
__attribute__((amdgpu_waves_per_eu(4, 8)))
void seven_neurons_mfma(
    const float* __restrict__ x,
    const _Float16* __restrict__ wsh, const float* __restrict__ wsb,
    const float* __restrict__ gamma, const float* __restrict__ beta,
    const float* __restrict__ W_out, const float* __restrict__ b_out,
    float* __restrict__ out)
{
    __shared__ __align__(16) unsigned char lds[45056 + 16 * 6656];  // 148 KB

    const int t = threadIdx.x;
    const int lane = t & 63, wv = t >> 6;                // wv 0..15
    const int lr = lane & 15, lk = lane >> 4;

    unsigned char* ldsW  = lds;                          // B1 at 0, B2 at 32K, B3 at 40K
    unsigned char* xslot = lds + 45056 + wv * 6656;      // 4 KB x double-buffer
    unsigned char* wslot = xslot + 4096;                 // H fp16 [16][72] / integ fp32 [16][25]

    // ---- biases (oldest in vmcnt queue; drained by prologue vmcnt(4))
    float b1v[4], b2v[4], b3v[2];
#pragma unroll 4
    for (int nt = 0; nt < 4; ++nt) { b1v[nt] = wsb[nt * 16 + lr]; b2v[nt] = wsb[64 + nt * 16 + lr]; }
#pragma unroll 2
    for (int nt = 0; nt < 2; ++nt) b3v[nt] = wsb[128 + nt * 16 + lr];

    // ---- stage ALL weight fragments (44 x 1KB) once
    const unsigned char* wsrc = (const unsigned char*)wsh;
#pragma unroll 1
    for (int f = wv; f < 44; f += 16)
        cp16(wsrc + (size_t)f * 1024 + lane * 16, ldsW + (size_t)f * 1024);

    // x source, PRE-SWIZZLED (rule #21): staging lane i covers LDS row i>>3,
    // granule i&7; linear DMA dest => fetch logical granule (i&7)^row.
    const int srow = lane >> 3;                      // 0..7
    const int sgr  = (lane & 7) ^ srow;              // swizzled granule
    const float* xsrc = x + ((size_t)blockIdx.x * NTILES * 256 + wv * 16 + srow) * 256 + sgr * 4;

    // chunks 0,1 of tile 0 (chunk g: src + (g>>3)*65536 + (g&7)*32; dst parity g&1)
    cp16(xsrc + 0,           xslot + 0);
    cp16(xsrc + 2048,        xslot + 1024);
    cp16(xsrc + 32,          xslot + 2048);
    cp16(xsrc + 32 + 2048,   xslot + 3072);

    asm volatile("s_waitcnt vmcnt(4)" ::: "memory");   // biases+weights done; x0,x1 in flight
    __builtin_amdgcn_sched_barrier(0);
    __builtin_amdgcn_s_barrier();                      // publish weights (no vmcnt(0) drain)

    // reader offsets (constant per lane): logical row lr, granules 2lk,2lk+1,
    // physical granule = logical ^ (lr&7)
    const int xoff0 = lr * 128 + (((2 * lk)     ^ (lr & 7)) << 4);
    const int xoff1 = lr * 128 + (((2 * lk + 1) ^ (lr & 7)) << 4);

#pragma unroll 1
    for (int it = 0; it < NTILES; ++it) {
        // ---- stage 1: h[16 rows] = spiral(x @ W_in^T + b1), K=256
        f32x4 acc1[4];
#pragma unroll 4
        for (int ni = 0; ni < 4; ++ni) acc1[ni] = (f32x4){0.f, 0.f, 0.f, 0.f};

#pragma unroll
        for (int k = 0; k < 8; ++k) {
            if (it == NTILES - 1 && k == 7)
                asm volatile("s_waitcnt vmcnt(0)" ::: "memory");
            else
                asm volatile("s_waitcnt vmcnt(2)" ::: "memory");
            __builtin_amdgcn_sched_barrier(0);

            const unsigned char* xc = xslot + (k & 1) * 2048;
            const f32x4 r0 = *reinterpret_cast<const f32x4*>(xc + xoff0);
            const f32x4 r1 = *reinterpret_cast<const f32x4*>(xc + xoff1);
            const f16x8 a = { (_Float16)r0[0], (_Float16)r0[1], (_Float16)r0[2], (_Float16)r0[3],
                              (_Float16)r1[0], (_Float16)r1[1], (_Float16)r1[2], (_Float16)r1[3] };

            // WAR fence: chunk-k LDS reads retired before refilling this buffer
            asm volatile("s_waitcnt lgkmcnt(0)" ::: "memory");
            __builtin_amdgcn_sched_barrier(0);
            const int g2 = it * 8 + k + 2;
            if (g2 < NTILES * 8) {
                const float* s0 = xsrc + (size_t)(g2 >> 3) * 65536 + (g2 & 7) * 32;
                cp16(s0,        xslot + (k & 1) * 2048);
                cp16(s0 + 2048, xslot + (k & 1) * 2048 + 1024);
            }

#pragma unroll 4
            for (int nt = 0; nt < 4; ++nt) {
                const f16x8 bf = *reinterpret_cast<const f16x8*>(
                    ldsW + (size_t)(k * 4 + nt) * 1024 + lane * 16);
                acc1[nt] = __builtin_amdgcn_mfma_f32_16x16x32_f16(a, bf, acc1[nt], 0, 0, 0);
            }
        }

        // epilogue 1: H fp16 [16][72] into work area (disjoint from x dbuf!)
        {
            _Float16* H = (_Float16*)wslot;
#pragma unroll 4
            for (int nt = 0; nt < 4; ++nt)
#pragma unroll 4
                for (int r = 0; r < 4; ++r) {
                    const int row = lk * 4 + r;                  // 0..15
                    const float v = phi_spiral(acc1[nt][r] + b1v[nt]);
                    H[row * 72 + nt * 16 + lr] = (_Float16)v;
                }
        }

        // ---- stage 2: comb = spiral(h @ Wn^T + b2), K=64 (all LDS)
        f32x4 acc2[4];
#pragma unroll 4
        for (int ni = 0; ni < 4; ++ni) acc2[ni] = (f32x4){0.f, 0.f, 0.f, 0.f};
#pragma unroll 2
        for (int ks = 0; ks < 2; ++ks) {
            const f16x8 a = *reinterpret_cast<const f16x8*>(
                wslot + lr * 144 + (ks * 32 + lk * 8) * 2);
#pragma unroll 4
            for (int nt = 0; nt < 4; ++nt) {
                const f16x8 bf = *reinterpret_cast<const f16x8*>(
                    ldsW + 32768 + (size_t)((ks * 4 + nt) * 64 + lane) * 16);
                acc2[nt] = __builtin_amdgcn_mfma_f32_16x16x32_f16(a, bf, acc2[nt], 0, 0, 0);
            }
        }
        {
            _Float16* H = (_Float16*)wslot;
#pragma unroll 4
            for (int nt = 0; nt < 4; ++nt)
#pragma unroll 4
                for (int r = 0; r < 4; ++r) {
                    const int row = lk * 4 + r;
                    const float v = phi_spiral(acc2[nt][r] + b2v[nt]);
                    H[row * 72 + nt * 16 + lr] = (_Float16)v;
                }
        }

        // ---- stage 3: integ = spiral(comb @ W_int^T + b3), K=64, N=32
        f32x4 acc3[2];
#pragma unroll 2
        for (int ni = 0; ni < 2; ++ni) acc3[ni] = (f32x4){0.f, 0.f, 0.f, 0.f};
#pragma unroll 2
        for (int ks = 0; ks < 2; ++ks) {
            const f16x8 a = *reinterpret_cast<const f16x8*>(
                wslot + lr * 144 + (ks * 32 + lk * 8) * 2);
#pragma unroll 2
            for (int nt = 0; nt < 2; ++nt) {
                const f16x8 bf = *reinterpret_cast<const f16x8*>(
                    ldsW + 40960 + (size_t)((ks * 2 + nt) * 64 + lane) * 16);
                acc3[nt] = __builtin_amdgcn_mfma_f32_16x16x32_f16(a, bf, acc3[nt], 0, 0, 0);
            }
        }
        // epilogue 3: integ fp32 [16][25] overlays H (in-wave WAR via lgkmcnt)
        {
            float* F = (float*)wslot;
#pragma unroll 2
            for (int nt = 0; nt < 2; ++nt)
#pragma unroll 4
                for (int r = 0; r < 4; ++r) {
                    const int col = nt * 16 + lr;
                    const int row = lk * 4 + r;
                    if (col < 21)
                        F[row * 25 + col] = phi_spiral(acc3[nt][r] + b3v[nt]);
                }
        }

        // ---- LayerNorm(21) + out: 4 threads/row, wave-private (r>>4 == wv)
        {
            const int r = t >> 2, p = t & 3;
            const float* my = (const float*)(lds + 45056 + (size_t)(r >> 4) * 6656 + 4096)
                              + (r & 15) * 25;
            float v[21];
#pragma unroll 21
            for (int o = 0; o < 21; ++o) v[o] = my[o];
            float mu = 0.f;
#pragma unroll 21
            for (int o = 0; o < 21; ++o) mu += v[o];
            mu *= (1.0f / 21.0f);
            float var = 0.f;
#pragma unroll 21
            for (int o = 0; o < 21; ++o) { float d = v[o] - mu; var = fmaf(d, d, var); }
            var *= (1.0f / 21.0f);
            const float rs = rsqrtf(var + 1e-5f);
            float acc = b_out[p];
#pragma unroll 21
            for (int o = 0; o < 21; ++o)
                acc = fmaf((v[o] - mu) * rs * gamma[o] + beta[o], W_out[p * 21 + o], acc);
            out[((size_t)blockIdx.x * NTILES + it) * 1024 + t] = acc;
        }
    }
}

extern "C" void kernel_launch(void* const* d_in, const int* in_sizes, int n_in,
                              void* d_out, int out_size, void* d_ws, size_t ws_size,
                              hipStream_t stream) {
    const float* x     = (const float*)d_in[0];
    const float* W_in  = (const float*)d_in[1];
    const float* b_in  = (const float*)d_in[2];
    const float* Wn    = (const float*)d_in[3];
    const float* bn    = (const float*)d_in[4];
    const float* W_int = (const float*)d_in[5];
    const float* b_int = (const float*)d_in[6];
    const float* gamma = (const float*)d_in[7];
    const float* beta  = (const float*)d_in[8];
    const float* W_out = (const float*)d_in[9];
    const float* b_out = (const float*)d_in[10];
    float* out = (float*)d_out;

    _Float16* wsh = (_Float16*)d_ws;
    float*    wsb = (float*)((char*)d_ws + WS_BIAS_BYTES);

    prep_kernel<<<12, 256, 0, stream>>>(W_in, b_in, Wn, bn, W_int, b_int, wsh, wsb);

    const int B = in_sizes[0] / 256;          // 262144 = 256 blocks x 4 tiles x 256 rows
    seven_neurons_mfma<<<B / (NTILES * 256), 1024, 0, stream>>>(
        x, wsh, wsb, gamma, beta, W_out, b_out, out);
}